// Round 4
// baseline (438.466 us; speedup 1.0000x reference)
//
#include <hip/hip_runtime.h>

// DIN attention layer: B=2048, L=200, E=128, H=64.  R4: kill spills + online softmax.
// One WG (256 thr) per batch row. B-fragments read from LDS per use (no 96-VGPR
// persistent frags -> no scratch spill). Keys HBM->reg->MFMA, wsum accumulated
// online (flash-style per-wave m/z rescale) so keys are never stored anywhere.
// LDS 37.7KB, 2 barriers, __launch_bounds__(256,4).

#define NB 2048
#define LE 128   // E
#define LH 64    // H
#define LL 200   // L

typedef short bf16x8 __attribute__((ext_vector_type(8)));
typedef float f32x4 __attribute__((ext_vector_type(4)));

__device__ __forceinline__ short f2bf(float f) {  // RNE float->bf16
  unsigned u = __float_as_uint(f);
  u += 0x7fffu + ((u >> 16) & 1u);
  return (short)(u >> 16);
}
__device__ __forceinline__ float bf2f(short h) {
  return __uint_as_float(((unsigned)(unsigned short)h) << 16);
}

struct __align__(16) SM {
  short wk[64 * 136];     // 17408 B: Wk[h][e], stride 136 (16B-aligned rows, bank-spread)
  short w2t[64 * 72];     // 9216 B:  W2T[c][k], stride 72
  short h1[4][16 * 72];   // 9216 B:  per-wave h1 transpose; tail reused as wred[4][130]
  float biasp[4][64];     // 1024 B
  int   smask[208];       // 832 B
};  // 37696 B -> 4 WG/CU (150.8KB of 160KB)

// ---- K0: b-independent weight prep into workspace ------------------------
// BD[h][e]=W1b-W1d ; Cq[h][e]=W1c ; AD[e][h]=W1a+W1d ; W2T[c][k]=W2[k][c] (bf16)
__global__ void k0_prep(const float* __restrict__ W1, const float* __restrict__ W2,
                        float* __restrict__ BD, float* __restrict__ Cq,
                        float* __restrict__ AD, short* __restrict__ W2T) {
  int idx = blockIdx.x * 256 + threadIdx.x;  // 32 blocks * 256 = 8192
  if (idx < 8192) {
    int h = idx >> 7, e = idx & 127;
    BD[idx] = W1[(128 + e) * LH + h] - W1[(384 + e) * LH + h];
    Cq[idx] = W1[(256 + e) * LH + h];
    int e2 = idx >> 6, h2 = idx & 63;
    AD[idx] = W1[e2 * LH + h2] + W1[(384 + e2) * LH + h2];
    if (idx < 4096) {
      int c = idx >> 6, k = idx & 63;
      W2T[idx] = f2bf(W2[k * LH + c]);
    }
  }
}

__global__ void __launch_bounds__(256, 4)
din_attn(const float* __restrict__ query, const float* __restrict__ keysg,
         const int* __restrict__ mask, const float* __restrict__ b1,
         const float* __restrict__ b2, const float* __restrict__ W3,
         const float* __restrict__ no_hist,
         const float* __restrict__ BD, const float* __restrict__ Cq,
         const float* __restrict__ AD, const short* __restrict__ W2T,
         float* __restrict__ out)
{
  __shared__ SM sm;
  const int b    = blockIdx.x;
  const int t    = threadIdx.x;
  const int lane = t & 63;
  const int wv   = t >> 6;
  const int col  = lane & 15;   // MFMA m/n index
  const int quad = lane >> 4;   // MFMA k-group

  const float* kb = keysg + (size_t)b * (LL * LE);

  // ---- prefetch first keys tile (mt = wv, rows < 64) so HBM streams early
  float4 pre[8];
  {
    const float* rp = kb + (wv * 16 + col) * LE;
    #pragma unroll
    for (int kt = 0; kt < 4; ++kt) {
      pre[2 * kt]     = *(const float4*)&rp[kt * 32 + quad * 8];
      pre[2 * kt + 1] = *(const float4*)&rp[kt * 32 + quad * 8 + 4];
    }
  }

  // ---- phase 0: smask, Wk build, W2T->LDS, bias1 partials
  if (t < 208) sm.smask[t] = (t < LL) ? mask[b * LL + t] : 0;

  {
    const int e0 = (t * 4) & 127;
    float4 qv = *(const float4*)&query[b * LE + e0];
    #pragma unroll
    for (int i = 0; i < 8; ++i) {
      int idx = t * 4 + i * 1024;
      int h = idx >> 7;
      float4 bd = *(const float4*)&BD[idx];
      float4 cq = *(const float4*)&Cq[idx];
      short4 wq = make_short4(f2bf(bd.x + qv.x * cq.x), f2bf(bd.y + qv.y * cq.y),
                              f2bf(bd.z + qv.z * cq.z), f2bf(bd.w + qv.w * cq.w));
      *(short4*)&sm.wk[h * 136 + e0] = wq;
    }
  }
  {  // W2T -> LDS (stride 72)
    int c = t >> 2, sg = (t & 3) * 16;
    *(bf16x8*)&sm.w2t[c * 72 + sg]     = *(const bf16x8*)&W2T[c * 64 + sg];
    *(bf16x8*)&sm.w2t[c * 72 + sg + 8] = *(const bf16x8*)&W2T[c * 64 + sg + 8];
  }
  {  // bias1 partial: wave wv sums its e-quarter for all 64 h (h = lane)
    float acc = 0.f;
    const float* adp = &AD[(wv * 32) * LH + lane];
    const float* qp  = &query[b * LE + wv * 32];
    #pragma unroll 8
    for (int e = 0; e < 32; ++e)
      acc = fmaf(qp[e], adp[e * LH], acc);
    sm.biasp[wv][lane] = acc;
  }
  __syncthreads();  // BARRIER 1

  float bias1r[4], b2r[4], w3r[4];
  #pragma unroll
  for (int n = 0; n < 4; ++n) {
    int h = n * 16 + col;
    bias1r[n] = b1[h] + sm.biasp[0][h] + sm.biasp[1][h] + sm.biasp[2][h] + sm.biasp[3][h];
    b2r[n] = b2[h];
    w3r[n] = W3[h];
  }

  // ---- main loop: wave wv owns tiles {wv, wv+4, wv+8} (+12 for wv==0).
  // Online softmax: running (mw, zw) per wave; acc[kt][x] holds
  // sum_l ex_l * keys[l][e], e = kt*32 + quad*8 + x, for this lane's rows.
  float acc[4][8];
  #pragma unroll
  for (int kt = 0; kt < 4; ++kt)
    #pragma unroll
    for (int x = 0; x < 8; ++x) acc[kt][x] = 0.f;
  float zw = 0.f, mw = -3.0e38f;
  short* h1w = &sm.h1[wv][0];

  const int nt = (wv == 0) ? 4 : 3;
  #pragma unroll 1
  for (int it = 0; it < nt; ++it) {
    int mt = wv + it * 4;
    int row = mt * 16 + col;
    int rowg = row < LL ? row : LL - 1;
    const float* rp = kb + rowg * LE;
    bf16x8 a[4];
    #pragma unroll
    for (int kt = 0; kt < 4; ++kt) {
      float4 v0, v1;
      if (it == 0) { v0 = pre[2 * kt]; v1 = pre[2 * kt + 1]; }
      else {
        v0 = *(const float4*)&rp[kt * 32 + quad * 8];
        v1 = *(const float4*)&rp[kt * 32 + quad * 8 + 4];
      }
      bf16x8 av;
      av[0] = f2bf(v0.x); av[1] = f2bf(v0.y); av[2] = f2bf(v0.z); av[3] = f2bf(v0.w);
      av[4] = f2bf(v1.x); av[5] = f2bf(v1.y); av[6] = f2bf(v1.z); av[7] = f2bf(v1.w);
      a[kt] = av;
    }
    // layer 1: fB1 frags read from LDS per use (no persistent frag regs)
    #pragma unroll
    for (int n = 0; n < 4; ++n) {
      f32x4 c1 = {0.f, 0.f, 0.f, 0.f};
      #pragma unroll
      for (int kt = 0; kt < 4; ++kt) {
        bf16x8 fb = *(const bf16x8*)&sm.wk[(n * 16 + col) * 136 + kt * 32 + quad * 8];
        c1 = __builtin_amdgcn_mfma_f32_16x16x32_bf16(a[kt], fb, c1, 0, 0, 0);
      }
      #pragma unroll
      for (int i = 0; i < 4; ++i)  // C layout: row=quad*4+i, col
        h1w[(quad * 4 + i) * 72 + n * 16 + col] =
            f2bf(fmaxf(c1[i] + bias1r[n], 0.f));
    }
    // layer 2+3: wave-local transpose via h1w
    bf16x8 a2[2];
    #pragma unroll
    for (int k2 = 0; k2 < 2; ++k2)
      a2[k2] = *(const bf16x8*)&h1w[col * 72 + k2 * 32 + quad * 8];
    float p[4] = {0.f, 0.f, 0.f, 0.f};
    #pragma unroll
    for (int n = 0; n < 4; ++n) {
      f32x4 c2 = {0.f, 0.f, 0.f, 0.f};
      bf16x8 f0 = *(const bf16x8*)&sm.w2t[(n * 16 + col) * 72 + quad * 8];
      bf16x8 f1 = *(const bf16x8*)&sm.w2t[(n * 16 + col) * 72 + 32 + quad * 8];
      c2 = __builtin_amdgcn_mfma_f32_16x16x32_bf16(a2[0], f0, c2, 0, 0, 0);
      c2 = __builtin_amdgcn_mfma_f32_16x16x32_bf16(a2[1], f1, c2, 0, 0, 0);
      #pragma unroll
      for (int i = 0; i < 4; ++i)
        p[i] = fmaf(fmaxf(c2[i] + b2r[n], 0.f), w3r[n], p[i]);  // b3 dropped
    }
    // reduce over h (16 cols): p[i] -> score(row = mt*16 + quad*4 + i)
    #pragma unroll
    for (int i = 0; i < 4; ++i)
      #pragma unroll
      for (int off = 1; off < 16; off <<= 1)
        p[i] += __shfl_xor(p[i], off);
    // route score(mt*16+col) to this lane: source lane (col>>2)*16+col, p[col&3]
    float v01 = (col & 1) ? p[1] : p[0];
    float v23 = (col & 1) ? p[3] : p[2];
    float vsel = (col & 2) ? v23 : v01;
    float sc = __shfl(vsel, (col >> 2) * 16 + col);
    int mk = sm.smask[row];
    float scm = mk ? sc : -3.0e38f;
    float tmax = scm;
    #pragma unroll
    for (int off = 1; off < 16; off <<= 1) tmax = fmaxf(tmax, __shfl_xor(tmax, off));
    // online rescale + accumulate
    float m_new = fmaxf(mw, tmax);
    float scale = __expf(mw - m_new);
    mw = m_new;
    zw *= scale;
    float ex = mk ? __expf(sc - m_new) : 0.f;
    zw += ex;
    #pragma unroll
    for (int kt = 0; kt < 4; ++kt)
      #pragma unroll
      for (int x = 0; x < 8; ++x)
        acc[kt][x] = fmaf(ex, bf2f(a[kt][x]), acc[kt][x] * scale);
  }

  // ---- reduce wave partials over 16 cols; publish (m,z,partial[128]) per wave
  #pragma unroll
  for (int kt = 0; kt < 4; ++kt)
    #pragma unroll
    for (int x = 0; x < 8; ++x)
      #pragma unroll
      for (int off = 1; off < 16; off <<= 1)
        acc[kt][x] += __shfl_xor(acc[kt][x], off);
  #pragma unroll
  for (int off = 1; off < 16; off <<= 1) zw += __shfl_xor(zw, off);

  float* wr = (float*)&sm.h1[wv][0];  // 130 floats, wave-private (h1w dead)
  if (col == 0) {
    #pragma unroll
    for (int kt = 0; kt < 4; ++kt) {
      *(float4*)&wr[kt * 32 + quad * 8] =
          make_float4(acc[kt][0], acc[kt][1], acc[kt][2], acc[kt][3]);
      *(float4*)&wr[kt * 32 + quad * 8 + 4] =
          make_float4(acc[kt][4], acc[kt][5], acc[kt][6], acc[kt][7]);
    }
  }
  if (lane == 0) { wr[128] = mw; wr[129] = zw; }
  __syncthreads();  // BARRIER 2

  // ---- cross-wave combine (threads 0..127, one per e)
  if (t < LE) {
    const float* w0 = (const float*)&sm.h1[0][0];  // wave stride 576 floats
    float m0 = w0[128], m1 = w0[576 + 128], m2 = w0[1152 + 128], m3 = w0[1728 + 128];
    float M = fmaxf(fmaxf(m0, m1), fmaxf(m2, m3));
    float s0 = __expf(m0 - M), s1 = __expf(m1 - M);
    float s2 = __expf(m2 - M), s3 = __expf(m3 - M);
    float s = s0 * w0[t] + s1 * w0[576 + t] + s2 * w0[1152 + t] + s3 * w0[1728 + t];
    float Z = s0 * w0[129] + s1 * w0[576 + 129] + s2 * w0[1152 + 129] + s3 * w0[1728 + 129];
    bool allpad = (M <= -1.0e38f);
    out[b * LE + t] = allpad ? no_hist[t] : s / Z;
  }
}

extern "C" void kernel_launch(void* const* d_in, const int* in_sizes, int n_in,
                              void* d_out, int out_size, void* d_ws, size_t ws_size,
                              hipStream_t stream) {
  (void)in_sizes; (void)n_in; (void)ws_size; (void)out_size;
  const float* query   = (const float*)d_in[0];
  const float* keysg   = (const float*)d_in[1];
  const int*   mask    = (const int*)d_in[2];
  const float* W1      = (const float*)d_in[3];
  const float* b1      = (const float*)d_in[4];
  const float* W2      = (const float*)d_in[5];
  const float* b2      = (const float*)d_in[6];
  const float* W3      = (const float*)d_in[7];
  // d_in[8] = b3: unused (softmax shift-invariant)
  const float* no_hist = (const float*)d_in[9];

  float* BD  = (float*)d_ws;            // 8192 f32
  float* Cq  = BD + 8192;               // 8192 f32
  float* AD  = Cq + 8192;               // 8192 f32
  short* W2T = (short*)(AD + 8192);     // 4096 bf16

  k0_prep<<<32, 256, 0, stream>>>(W1, W2, BD, Cq, AD, W2T);
  din_attn<<<NB, 256, 0, stream>>>(query, keysg, mask, b1, b2, W3, no_hist,
                                   BD, Cq, AD, W2T, (float*)d_out);
}

// Round 5
// 383.167 us; speedup vs baseline: 1.1443x; 1.1443x over previous
//
#include <hip/hip_runtime.h>

// DIN attention layer: B=2048, L=200, E=128, H=64.  R5: kill scratch (SROA fix).
// R1-R4 all moved 130-175MB/dispatch through scratch because private ARRAYS
// (fB1[4][4], acc[4][8], pre[8], r0[13]) indexed by loop vars never get
// SROA-promoted (unroll runs after SROA) -> allocas -> scratch memory ops.
// R5: zero private arrays. All state is named ext_vector/scalar SSA values;
// per-n/kt loops expanded via macros with literal indices. Structure = R4:
// online softmax, 2 barriers, B-frags read from LDS per use.

#define NB 2048
#define LE 128   // E
#define LH 64    // H
#define LL 200   // L

typedef short bf16x8 __attribute__((ext_vector_type(8)));
typedef float f32x4 __attribute__((ext_vector_type(4)));

__device__ __forceinline__ short f2bf(float f) {  // RNE float->bf16
  unsigned u = __float_as_uint(f);
  u += 0x7fffu + ((u >> 16) & 1u);
  return (short)(u >> 16);
}
__device__ __forceinline__ float bf2f(short h) {
  return __uint_as_float(((unsigned)(unsigned short)h) << 16);
}

struct __align__(16) SM {
  short wk[64 * 136];     // 17408 B: Wk[h][e], stride 136
  short w2t[64 * 72];     // 9216 B:  W2T[c][k], stride 72
  short h1[4][16 * 72];   // 9216 B:  per-wave h1 transpose; reused as wred
  float biasp[4][64];     // 1024 B
  int   smask[208];       // 832 B
};  // 37696 B

// ---- K0: b-independent weight prep into workspace ------------------------
__global__ void k0_prep(const float* __restrict__ W1, const float* __restrict__ W2,
                        float* __restrict__ BD, float* __restrict__ Cq,
                        float* __restrict__ AD, short* __restrict__ W2T) {
  int idx = blockIdx.x * 256 + threadIdx.x;  // 32 blocks * 256 = 8192
  if (idx < 8192) {
    int h = idx >> 7, e = idx & 127;
    BD[idx] = W1[(128 + e) * LH + h] - W1[(384 + e) * LH + h];
    Cq[idx] = W1[(256 + e) * LH + h];
    int e2 = idx >> 6, h2 = idx & 63;
    AD[idx] = W1[e2 * LH + h2] + W1[(384 + e2) * LH + h2];
    if (idx < 4096) {
      int c = idx >> 6, k = idx & 63;
      W2T[idx] = f2bf(W2[k * LH + c]);
    }
  }
}

#define MFMA(A, B, C) __builtin_amdgcn_mfma_f32_16x16x32_bf16((A), (B), (C), 0, 0, 0)

#define LOAD8(RP, V0, V1, V2, V3, V4, V5, V6, V7)          \
  float4 V0 = *(const float4*)&(RP)[quad * 8];             \
  float4 V1 = *(const float4*)&(RP)[quad * 8 + 4];         \
  float4 V2 = *(const float4*)&(RP)[32 + quad * 8];        \
  float4 V3 = *(const float4*)&(RP)[32 + quad * 8 + 4];    \
  float4 V4 = *(const float4*)&(RP)[64 + quad * 8];        \
  float4 V5 = *(const float4*)&(RP)[64 + quad * 8 + 4];    \
  float4 V6 = *(const float4*)&(RP)[96 + quad * 8];        \
  float4 V7 = *(const float4*)&(RP)[96 + quad * 8 + 4];

#define PACK_A(A, VA, VB)                                           \
  A[0] = f2bf(VA.x); A[1] = f2bf(VA.y); A[2] = f2bf(VA.z);          \
  A[3] = f2bf(VA.w); A[4] = f2bf(VB.x); A[5] = f2bf(VB.y);          \
  A[6] = f2bf(VB.z); A[7] = f2bf(VB.w);

#define L1_N(N, BB)                                                          \
  { f32x4 c1 = {0.f, 0.f, 0.f, 0.f};                                         \
    const short* wkr = &sm.wk[((N) * 16 + col) * 136 + quad * 8];            \
    c1 = MFMA(a0, *(const bf16x8*)&wkr[0],  c1);                             \
    c1 = MFMA(a1, *(const bf16x8*)&wkr[32], c1);                             \
    c1 = MFMA(a2_, *(const bf16x8*)&wkr[64], c1);                            \
    c1 = MFMA(a3_, *(const bf16x8*)&wkr[96], c1);                            \
    h1w[(quad * 4 + 0) * 72 + (N) * 16 + col] = f2bf(fmaxf(c1[0] + (BB), 0.f)); \
    h1w[(quad * 4 + 1) * 72 + (N) * 16 + col] = f2bf(fmaxf(c1[1] + (BB), 0.f)); \
    h1w[(quad * 4 + 2) * 72 + (N) * 16 + col] = f2bf(fmaxf(c1[2] + (BB), 0.f)); \
    h1w[(quad * 4 + 3) * 72 + (N) * 16 + col] = f2bf(fmaxf(c1[3] + (BB), 0.f)); }

#define L2_N(N, B2S, W3S)                                                    \
  { f32x4 c2 = {0.f, 0.f, 0.f, 0.f};                                         \
    const short* w2r = &sm.w2t[((N) * 16 + col) * 72 + quad * 8];            \
    c2 = MFMA(h0,  *(const bf16x8*)&w2r[0],  c2);                            \
    c2 = MFMA(h1r, *(const bf16x8*)&w2r[32], c2);                            \
    p0 = fmaf(fmaxf(c2[0] + (B2S), 0.f), (W3S), p0);                         \
    p1 = fmaf(fmaxf(c2[1] + (B2S), 0.f), (W3S), p1);                         \
    p2 = fmaf(fmaxf(c2[2] + (B2S), 0.f), (W3S), p2);                         \
    p3 = fmaf(fmaxf(c2[3] + (B2S), 0.f), (W3S), p3); }

#define REDC(X) X += __shfl_xor(X, 1); X += __shfl_xor(X, 2); \
                X += __shfl_xor(X, 4); X += __shfl_xor(X, 8);

#define REDV(V) { float r_;                       \
  r_ = V[0]; REDC(r_); V[0] = r_;                 \
  r_ = V[1]; REDC(r_); V[1] = r_;                 \
  r_ = V[2]; REDC(r_); V[2] = r_;                 \
  r_ = V[3]; REDC(r_); V[3] = r_; }

#define ACC_UPD(LO, HI, A)                              \
  LO[0] = fmaf(ex, bf2f((A)[0]), LO[0] * scale);        \
  LO[1] = fmaf(ex, bf2f((A)[1]), LO[1] * scale);        \
  LO[2] = fmaf(ex, bf2f((A)[2]), LO[2] * scale);        \
  LO[3] = fmaf(ex, bf2f((A)[3]), LO[3] * scale);        \
  HI[0] = fmaf(ex, bf2f((A)[4]), HI[0] * scale);        \
  HI[1] = fmaf(ex, bf2f((A)[5]), HI[1] * scale);        \
  HI[2] = fmaf(ex, bf2f((A)[6]), HI[2] * scale);        \
  HI[3] = fmaf(ex, bf2f((A)[7]), HI[3] * scale);

#define PROC_TILE(MT, V0, V1, V2, V3, V4, V5, V6, V7)                        \
  { bf16x8 a0, a1, a2_, a3_;                                                 \
    PACK_A(a0, V0, V1) PACK_A(a1, V2, V3)                                    \
    PACK_A(a2_, V4, V5) PACK_A(a3_, V6, V7)                                  \
    L1_N(0, bias10) L1_N(1, bias11) L1_N(2, bias12) L1_N(3, bias13)          \
    bf16x8 h0  = *(const bf16x8*)&h1w[col * 72 + quad * 8];                  \
    bf16x8 h1r = *(const bf16x8*)&h1w[col * 72 + 32 + quad * 8];             \
    float p0 = 0.f, p1 = 0.f, p2 = 0.f, p3 = 0.f;                            \
    L2_N(0, b20, w30) L2_N(1, b21, w31) L2_N(2, b22, w32) L2_N(3, b23, w33)  \
    REDC(p0) REDC(p1) REDC(p2) REDC(p3)                                      \
    float v01 = (col & 1) ? p1 : p0;                                         \
    float v23 = (col & 1) ? p3 : p2;                                         \
    float vsel = (col & 2) ? v23 : v01;                                      \
    float sc = __shfl(vsel, (col >> 2) * 16 + col);                          \
    int mk = sm.smask[(MT) * 16 + col];                                      \
    float scm = mk ? sc : -3.0e38f;                                          \
    float tmax = scm;                                                        \
    tmax = fmaxf(tmax, __shfl_xor(tmax, 1));                                 \
    tmax = fmaxf(tmax, __shfl_xor(tmax, 2));                                 \
    tmax = fmaxf(tmax, __shfl_xor(tmax, 4));                                 \
    tmax = fmaxf(tmax, __shfl_xor(tmax, 8));                                 \
    float m_new = fmaxf(mw, tmax);                                           \
    float scale = __expf(mw - m_new);                                        \
    mw = m_new;                                                              \
    float ex = mk ? __expf(sc - m_new) : 0.f;                                \
    zw = zw * scale + ex;                                                    \
    ACC_UPD(ac0, ac1, a0) ACC_UPD(ac2, ac3, a1)                              \
    ACC_UPD(ac4, ac5, a2_) ACC_UPD(ac6, ac7, a3_) }

__global__ void __launch_bounds__(256, 3)
din_attn(const float* __restrict__ query, const float* __restrict__ keysg,
         const int* __restrict__ mask, const float* __restrict__ b1,
         const float* __restrict__ b2, const float* __restrict__ W3,
         const float* __restrict__ no_hist,
         const float* __restrict__ BD, const float* __restrict__ Cq,
         const float* __restrict__ AD, const short* __restrict__ W2T,
         float* __restrict__ out)
{
  __shared__ SM sm;
  const int b    = blockIdx.x;
  const int t    = threadIdx.x;
  const int lane = t & 63;
  const int wv   = t >> 6;
  const int col  = lane & 15;   // MFMA m/n index
  const int quad = lane >> 4;   // MFMA k-group

  const float* kb = keysg + (size_t)b * (LL * LE);

  // ---- prefetch tile mt=wv (rows < 64, always valid): 8 named float4s
  const float* rp0 = kb + (wv * 16 + col) * LE;
  LOAD8(rp0, q0, q1, q2, q3, q4, q5, q6, q7)

  // ---- phase 0: smask, Wk build, W2T->LDS, bias1 partials (no private arrays)
  if (t < 208) sm.smask[t] = (t < LL) ? mask[b * LL + t] : 0;
  {
    const int e0 = (t * 4) & 127;
    float4 qv = *(const float4*)&query[b * LE + e0];
    #pragma unroll
    for (int i = 0; i < 8; ++i) {
      int idx = t * 4 + i * 1024;
      int h = idx >> 7;
      float4 bd = *(const float4*)&BD[idx];
      float4 cq = *(const float4*)&Cq[idx];
      short4 wq = make_short4(f2bf(bd.x + qv.x * cq.x), f2bf(bd.y + qv.y * cq.y),
                              f2bf(bd.z + qv.z * cq.z), f2bf(bd.w + qv.w * cq.w));
      *(short4*)&sm.wk[h * 136 + e0] = wq;
    }
  }
  {  // W2T -> LDS (stride 72)
    int c = t >> 2, sg = (t & 3) * 16;
    *(bf16x8*)&sm.w2t[c * 72 + sg]     = *(const bf16x8*)&W2T[c * 64 + sg];
    *(bf16x8*)&sm.w2t[c * 72 + sg + 8] = *(const bf16x8*)&W2T[c * 64 + sg + 8];
  }
  {  // bias1 partial: wave wv sums its e-quarter for all 64 h (h = lane)
    float acc = 0.f;
    const float* adp = &AD[(wv * 32) * LH + lane];
    const float* qp  = &query[b * LE + wv * 32];
    #pragma unroll 8
    for (int e = 0; e < 32; ++e)
      acc = fmaf(qp[e], adp[e * LH], acc);
    sm.biasp[wv][lane] = acc;
  }
  __syncthreads();  // BARRIER 1

  // per-lane scalars (named, literal-indexed)
  float bias10, bias11, bias12, bias13, b20, b21, b22, b23, w30, w31, w32, w33;
#define BPREP(N, BV, B2V, W3V)                                               \
  { int hh = (N) * 16 + col;                                                 \
    BV = b1[hh] + sm.biasp[0][hh] + sm.biasp[1][hh] + sm.biasp[2][hh]        \
       + sm.biasp[3][hh];                                                    \
    B2V = b2[hh]; W3V = W3[hh]; }
  BPREP(0, bias10, b20, w30) BPREP(1, bias11, b21, w31)
  BPREP(2, bias12, b22, w32) BPREP(3, bias13, b23, w33)
#undef BPREP

  // ---- online-softmax state: all named SSA values
  f32x4 ac0 = {0.f,0.f,0.f,0.f}, ac1 = ac0, ac2 = ac0, ac3 = ac0;
  f32x4 ac4 = ac0, ac5 = ac0, ac6 = ac0, ac7 = ac0;
  float zw = 0.f, mw = -3.0e38f;
  short* h1w = &sm.h1[wv][0];

  // tiles wv, wv+4, wv+8 (+12 for wave 0) — straight-line, no barriers
  PROC_TILE(wv, q0, q1, q2, q3, q4, q5, q6, q7)
  {
    const float* rp = kb + ((wv + 4) * 16 + col) * LE;   // rows < 128
    LOAD8(rp, v0, v1, v2, v3, v4, v5, v6, v7)
    PROC_TILE(wv + 4, v0, v1, v2, v3, v4, v5, v6, v7)
  }
  {
    const float* rp = kb + ((wv + 8) * 16 + col) * LE;   // rows < 192
    LOAD8(rp, u0, u1, u2, u3, u4, u5, u6, u7)
    PROC_TILE(wv + 8, u0, u1, u2, u3, u4, u5, u6, u7)
  }
  if (wv == 0) {
    int row = 192 + col;
    const float* rp = kb + (row < LL ? row : LL - 1) * LE;  // clamp; smask zeroes
    LOAD8(rp, w0, w1, w2, w3v_, w4, w5, w6, w7)
    PROC_TILE(12, w0, w1, w2, w3v_, w4, w5, w6, w7)
  }

  // ---- reduce wave partials over 16 cols; publish (partial[128], m, z)
  REDV(ac0) REDV(ac1) REDV(ac2) REDV(ac3)
  REDV(ac4) REDV(ac5) REDV(ac6) REDV(ac7)
  REDC(zw)

  float* wr = (float*)&sm.h1[wv][0];  // 130 floats, wave-private (h1w dead)
  if (col == 0) {
    *(f32x4*)&wr[ 0 + quad * 8]     = ac0;
    *(f32x4*)&wr[ 0 + quad * 8 + 4] = ac1;
    *(f32x4*)&wr[32 + quad * 8]     = ac2;
    *(f32x4*)&wr[32 + quad * 8 + 4] = ac3;
    *(f32x4*)&wr[64 + quad * 8]     = ac4;
    *(f32x4*)&wr[64 + quad * 8 + 4] = ac5;
    *(f32x4*)&wr[96 + quad * 8]     = ac6;
    *(f32x4*)&wr[96 + quad * 8 + 4] = ac7;
  }
  if (lane == 0) { wr[128] = mw; wr[129] = zw; }
  __syncthreads();  // BARRIER 2

  // ---- cross-wave combine (threads 0..127, one per e)
  if (t < LE) {
    const float* c0 = (const float*)&sm.h1[0][0];  // wave stride 576 floats
    float m0 = c0[128], m1 = c0[576 + 128], m2 = c0[1152 + 128], m3 = c0[1728 + 128];
    float M = fmaxf(fmaxf(m0, m1), fmaxf(m2, m3));
    float s0 = __expf(m0 - M), s1 = __expf(m1 - M);
    float s2 = __expf(m2 - M), s3 = __expf(m3 - M);
    float s = s0 * c0[t] + s1 * c0[576 + t] + s2 * c0[1152 + t] + s3 * c0[1728 + t];
    float Z = s0 * c0[129] + s1 * c0[576 + 129] + s2 * c0[1152 + 129] + s3 * c0[1728 + 129];
    bool allpad = (M <= -1.0e38f);
    out[b * LE + t] = allpad ? no_hist[t] : s / Z;
  }
}

extern "C" void kernel_launch(void* const* d_in, const int* in_sizes, int n_in,
                              void* d_out, int out_size, void* d_ws, size_t ws_size,
                              hipStream_t stream) {
  (void)in_sizes; (void)n_in; (void)ws_size; (void)out_size;
  const float* query   = (const float*)d_in[0];
  const float* keysg   = (const float*)d_in[1];
  const int*   mask    = (const int*)d_in[2];
  const float* W1      = (const float*)d_in[3];
  const float* b1      = (const float*)d_in[4];
  const float* W2      = (const float*)d_in[5];
  const float* b2      = (const float*)d_in[6];
  const float* W3      = (const float*)d_in[7];
  // d_in[8] = b3: unused (softmax shift-invariant)
  const float* no_hist = (const float*)d_in[9];

  float* BD  = (float*)d_ws;            // 8192 f32
  float* Cq  = BD + 8192;               // 8192 f32
  float* AD  = Cq + 8192;               // 8192 f32
  short* W2T = (short*)(AD + 8192);     // 4096 bf16

  k0_prep<<<32, 256, 0, stream>>>(W1, W2, BD, Cq, AD, W2T);
  din_attn<<<NB, 256, 0, stream>>>(query, keysg, mask, b1, b2, W3, no_hist,
                                   BD, Cq, AD, W2T, (float*)d_out);
}